// Round 3
// baseline (680.296 us; speedup 1.0000x reference)
//
#include <hip/hip_runtime.h>
#include <stdint.h>

#define NB 2048
#define OBSD 256
#define POP 10
#define NIN 2560       // OBS_DIM * POP_DIM
#define H 256          // HID1 == HID2
#define OUTP 80        // ACT_DIM * DE_POP
#define TS 25
#define NGRP 5         // encoder groups of 512 neurons
#define CAP 320        // record window slots (windowed chunk loop exact for any input)

typedef __attribute__((ext_vector_type(2))) float f2;

// correctly-rounded fp32 exp (fp64 exp then round) — matches SVML high-accuracy
// expf that numpy dispatches to on AVX512 hosts (validated r8: absmax 4.8e-7).
__device__ __forceinline__ float exp_cr(float x) {
    return (float)exp((double)x);
}

__device__ __forceinline__ int rfl(int v) {
    return __builtin_amdgcn_readfirstlane(v);
}

// HALF-accumulator: 12 elems as 6 float2 pairs + 1 scalar (25th elem, hi half
// only; lo half's .last accumulates a dead value — harmless, keeps one code path).
struct AccH {
    f2 p[6];
    float last;
};

__device__ __forceinline__ void acch_zero(AccH& a) {
    #pragma unroll
    for (int i = 0; i < 6; ++i) { a.p[i].x = 0.0f; a.p[i].y = 0.0f; }
    a.last = 0.0f;
}

// fold part into acc (per-element RN add — identical FP per element to the
// full-25 fold since folds are elementwise), zero part
__device__ __forceinline__ void acch_fold(AccH& acc, AccH& part) {
    #pragma unroll
    for (int i = 0; i < 6; ++i) {
        acc.p[i].x = __fadd_rn(acc.p[i].x, part.p[i].x);
        acc.p[i].y = __fadd_rn(acc.p[i].y, part.p[i].y);
        part.p[i].x = 0.0f; part.p[i].y = 0.0f;
    }
    acc.last = __fadd_rn(acc.last, part.last);
    part.last = 0.0f;
}

// 12(+1)-term fma on half a record: 3 x ds_read_b128 + 6 pk fma + 1 scalar fma.
// Per-element bitwise == scalar fmaf == the r0/r1 full-width path.
__device__ __forceinline__ void fma_half(float w, const float* __restrict__ rec,
                                         float lastv, AccH& a) {
    f2 wp; wp.x = w; wp.y = w;
    #pragma unroll
    for (int i = 0; i < 3; ++i) {
        float4 q = ((const float4*)rec)[i];
        f2 lo; lo.x = q.x; lo.y = q.y;
        f2 hi; hi.x = q.z; hi.y = q.w;
#if __has_builtin(__builtin_elementwise_fma)
        a.p[2 * i]     = __builtin_elementwise_fma(wp, lo, a.p[2 * i]);
        a.p[2 * i + 1] = __builtin_elementwise_fma(wp, hi, a.p[2 * i + 1]);
#else
        a.p[2 * i].x = fmaf(w, lo.x, a.p[2 * i].x);
        a.p[2 * i].y = fmaf(w, lo.y, a.p[2 * i].y);
        a.p[2 * i + 1].x = fmaf(w, hi.x, a.p[2 * i + 1].x);
        a.p[2 * i + 1].y = fmaf(w, hi.y, a.p[2 * i + 1].y);
#endif
    }
    a.last = fmaf(w, lastv, a.last);
}

// write one row record: 24 spike bit-floats (6 float4s, built one at a time to
// keep the transient live set small) + 25th float separate
__device__ __forceinline__ void write_rec(float* __restrict__ recs, float* __restrict__ rec24,
                                          int pos, uint32_t m) {
    float4* dst = (float4*)&recs[pos * 24];
    #pragma unroll
    for (int p = 0; p < 6; ++p) {
        float4 v;
        v.x = (m >> (4 * p)) & 1u ? 1.0f : 0.0f;
        v.y = (m >> (4 * p + 1)) & 1u ? 1.0f : 0.0f;
        v.z = (m >> (4 * p + 2)) & 1u ? 1.0f : 0.0f;
        v.w = (m >> (4 * p + 3)) & 1u ? 1.0f : 0.0f;
        dst[p] = v;
    }
    rec24[pos] = (m >> 24) & 1u ? 1.0f : 0.0f;
}

// sorted-index event walk, 2-deep weight prefetch, macro form (textual — no
// reference params; r1's aliased-reference walk and r2's over-budget live set
// both caused catastrophic accumulator spills). DOFOLD is a literal 0/1.
// Uses in-scope: idxL, rec24, recoff, t256, accW, partW, nextB.
#define WALK_BODY(CNT, WT, DOFOLD, TGT)                                       \
  do {                                                                        \
    const int _n = (CNT);                                                     \
    int _pi0 = 0, _pi1 = 0; float _pw0 = 0, _pw1 = 0;                         \
    if (_n > 0) { _pi0 = rfl(idxL[0]); _pw0 = (WT)[_pi0 + t256]; }            \
    if (_n > 1) { _pi1 = rfl(idxL[1]); _pw1 = (WT)[_pi1 + t256]; }            \
    int _j = 0;                                                               \
    for (; _j + 2 <= _n; _j += 2) {                                           \
      int _c0 = _pi0, _c1 = _pi1; float _w0 = _pw0, _w1 = _pw1;               \
      if (_j + 2 < _n) { _pi0 = rfl(idxL[_j + 2]); _pw0 = (WT)[_pi0 + t256]; } \
      if (_j + 3 < _n) { _pi1 = rfl(idxL[_j + 3]); _pw1 = (WT)[_pi1 + t256]; } \
      if (DOFOLD) { while (_c0 >= nextB) { acch_fold(accW, partW); nextB += 320 * H; } } \
      fma_half(_w0, recoff + _j * 24, rec24[_j], TGT);                        \
      if (DOFOLD) { while (_c1 >= nextB) { acch_fold(accW, partW); nextB += 320 * H; } } \
      fma_half(_w1, recoff + (_j + 1) * 24, rec24[_j + 1], TGT);              \
    }                                                                         \
    for (; _j < _n; ++_j) {                                                   \
      int _ii = rfl(idxL[_j]); float _wv = (WT)[_ii + t256];                  \
      if (DOFOLD) { while (_ii >= nextB) { acch_fold(accW, partW); nextB += 320 * H; } } \
      fma_half(_wv, recoff + _j * 24, rec24[_j], TGT);                        \
    }                                                                         \
  } while (0)

// ---------------- K0: COALESCED tiled transposes into fp32 [k][n] layouts ----------------
__global__ __launch_bounds__(256) void k0_transpose(
    const float* __restrict__ w1, const float* __restrict__ w2, const float* __restrict__ w3,
    float* __restrict__ w1t, float* __restrict__ w2t, float* __restrict__ w3t)
{
    __shared__ float tile[32][33];
    int bid = blockIdx.x;
    const float* src; float* dst; int R, C, tr, tc;
    if (bid < 640)      { src = w1; dst = w1t; R = 256; C = NIN; tr = bid / 80; tc = bid % 80; }
    else if (bid < 704) { int t = bid - 640; src = w2; dst = w2t; R = 256; C = 256; tr = t / 8; tc = t % 8; }
    else                { int t = bid - 704; src = w3; dst = w3t; R = OUTP; C = 256; tr = t / 8; tc = t % 8; }
    const int tx = threadIdx.x & 31, ty = threadIdx.x >> 5;
    const int r0 = tr * 32, c0 = tc * 32;
    #pragma unroll
    for (int i = 0; i < 4; ++i) {
        int r = r0 + ty + i * 8, c = c0 + tx;
        if (r < R && c < C) tile[ty + i * 8][tx] = src[r * C + c];
    }
    __syncthreads();
    // dst is [C][R]
    #pragma unroll
    for (int i = 0; i < 4; ++i) {
        int c = c0 + ty + i * 8, r = r0 + tx;
        if (c < C && r < R) dst[c * R + r] = tile[tx][ty + i * 8];
    }
}

// One LIF step, numpy-faithful per-op rounding. vth feeds ONLY the comparison,
// so decide the spike via certified interval from fast fp32 exp (~3 ulp) on a
// division-free argument d*(1/3); margin widened to cover the extra
// ~1.5e-7*|ag| relative arg error. Exact __fdiv_rn + exp_cr fallback only when
// |v - vth_a| <= delta (rare) — decisions provably identical.
__device__ __forceinline__ void lif_step(float x, float bv, float& c, float& v, float& s) {
    float cn = __fadd_rn(__fadd_rn(__fmul_rn(c, 0.5f), x), bv);
    c = cn;
    float vp = v;
    float t  = __fmul_rn(__fmul_rn(vp, 0.75f), __fadd_rn(1.0f, -s));
    float vn = __fadd_rn(t, cn);
    float d  = __fadd_rn(vp, -vn);
    v = vn;
    float ag_f  = __fmul_rn(d, 0.33333334f);        // fast approx of d/3
    float ex_a  = __expf(ag_f);                     // fast f32 exp (v_exp_f32)
    float vth_a = 0.25f + 0.5f * (ex_a - 1.0f);
    float delta = (1e-5f + 1e-6f * fabsf(ag_f)) * (ex_a + fabsf(vth_a) + 1.0f);
    if (vn > vth_a + delta) {
        s = 1.0f;
    } else if (vn < vth_a - delta) {
        s = 0.0f;
    } else {                                        // exact fallback (rare)
        float ag  = __fdiv_rn(d, 3.0f);
        float ex  = exp_cr(ag);
        float vth = __fadd_rn(0.25f, __fmul_rn(0.5f, __fadd_rn(ex, -1.0f)));
        s = (vn > vth) ? 1.0f : 0.0f;
    }
}

// ---------------- K1: fused, TIMESTEP-SPLIT 512-thread blocks ----------------
// Threads 0-255 own timesteps 0-11 of neuron (tid&255); threads 256-511 own
// timesteps 12-24. Per-element fma sequence and {320x8} fold order identical
// to the full-width kernel -> bit-identical results. 4 blocks/CU x 8 waves =
// 32 waves/CU (100%); grid 1024 blocks x 2 batch rows = one full-residency round.
__global__ __launch_bounds__(512, 8) void k1_fused(
    const float* __restrict__ obs, const float* __restrict__ emean, const float* __restrict__ estd,
    const float* __restrict__ w1t, const float* __restrict__ w2t, const float* __restrict__ w3t,
    const float* __restrict__ b1, const float* __restrict__ b2, const float* __restrict__ b3,
    const float* __restrict__ dw, const float* __restrict__ db, float* __restrict__ out)
{
    __shared__ __align__(16) float recs[CAP * 24];  // 30,720 B records; xbuf aliases head
    __shared__ float rec24[CAP];                    //  1,280 B 25th floats
    __shared__ int   idxL[CAP];                     //  1,280 B premult indices
    __shared__ uint32_t cntA[NGRP * 8];             //    160 B per-group per-wave counts
    __shared__ uint32_t gbase[NGRP + 1];            //     24 B group position prefix
    __shared__ uint32_t waveCnt[8];
    __shared__ float cnt3[OUTP];

    float* xbuf = recs;                             // [256][13] exchange, aliased (13,312 B)

    const int tid = threadIdx.x;
    const int wave = tid >> 6, lane = tid & 63;
    const int t256 = tid & 255;
    const int isHi = tid >> 8;                      // 0: steps 0-11, 1: steps 12-24
    const unsigned long long below = (1ull << lane) - 1ull;
    const float* recoff0 = recs + (isHi ? 12 : 0);  // half-record base offset

    for (int rr = 0; rr < 2; ++rr) {
        const int b = (blockIdx.x << 1) | rr;
        __syncthreads();                            // prior row's LDS reads done

        // ---- Phase A: population encoding, numpy-faithful fp32 op-by-op.
        // Monotonicity screen: arg < -3.23 => a < 0.0396 => 25a(1+eps) < 0.991
        // < 0.999 => mask provably 0 with NO exp call (validated r17). ----
        uint32_t msk[NGRP];
        for (int k = 0; k < NGRP; ++k) {
            int i = k * 512 + tid;
            int o = i / 10;
            float x  = obs[b * OBSD + o];
            float mu = emean[i];
            float sd = estd[i];
            float dd = __fadd_rn(x, -mu);
            float d2 = __fmul_rn(dd, dd);
            float nm = __fmul_rn(-0.5f, d2);
            float dn = __fmul_rn(sd, sd);
            float arg = __fdiv_rn(nm, dn);
            uint32_t m = 0;
            if (arg >= -3.23f) {
                float a  = exp_cr(arg);
                float volt = 0.0f;
                #pragma unroll
                for (int t = 0; t < TS; ++t) {
                    volt = __fadd_rn(volt, a);
                    if (volt > 0.999f) { m |= (1u << t); volt = __fadd_rn(volt, -0.999f); }
                }
            }
            msk[k] = m;
            unsigned long long bal = __ballot(m != 0u);
            if (lane == 0) cntA[k * 8 + wave] = (uint32_t)__popcll(bal);
        }
        __syncthreads();
        if (tid == 0) {                             // group position prefix sums
            uint32_t run = 0;
            #pragma unroll
            for (int k = 0; k < NGRP; ++k) {
                gbase[k] = run;
                uint32_t s = 0;
                #pragma unroll
                for (int w = 0; w < 8; ++w) s += cntA[k * 8 + w];
                run += s;
            }
            gbase[NGRP] = run;
        }
        __syncthreads();
        const int nTot = (int)gbase[NGRP];

        // ---- Phase B: event GEMM1, windowed chunk loop over global sorted
        // positions. Fold boundaries {320 x 8} ride on premult idx values —
        // identical FP order per element. ----
        AccH accW, partW;
        acch_zero(accW); acch_zero(partW);
        int nextB = 320 * H;
        const float* recoff = recoff0;

        for (int start = 0; start < nTot; start += CAP) {
            const int end = (nTot - start < CAP) ? nTot : start + CAP;
            const int count = end - start;
            #pragma unroll
            for (int k = 0; k < NGRP; ++k) {
                int gb = (int)gbase[k], ge = (int)gbase[k + 1];
                if (ge <= start || gb >= end) continue;
                uint32_t m = msk[k];
                unsigned long long bal = __ballot(m != 0u);
                if (m) {
                    int pre = 0;
                    #pragma unroll
                    for (int w = 0; w < 8; ++w) if (w < wave) pre += (int)cntA[k * 8 + w];
                    int pos = gb + pre + (int)__popcll(bal & below);
                    if (pos >= start && pos < end) {
                        int slot = pos - start;
                        idxL[slot] = (k * 512 + tid) * H;
                        write_rec(recs, rec24, slot, m);
                    }
                }
            }
            __syncthreads();                        // records complete
            WALK_BODY(count, w1t, 1, partW);
            __syncthreads();                        // walk reads done
        }
        acch_fold(accW, partW);                     // final fold

        // ---- exchange + C1: layer-1 LIF (lower half), all 25 steps ----
        if (isHi) {
            #pragma unroll
            for (int i = 0; i < 6; ++i) {
                xbuf[t256 * 13 + 2 * i]     = accW.p[i].x;
                xbuf[t256 * 13 + 2 * i + 1] = accW.p[i].y;
            }
            xbuf[t256 * 13 + 12] = accW.last;
        }
        __syncthreads();
        uint32_t m1 = 0;
        if (!isHi) {
            float cur[TS];
            #pragma unroll
            for (int i = 0; i < 6; ++i) { cur[2 * i] = accW.p[i].x; cur[2 * i + 1] = accW.p[i].y; }
            #pragma unroll
            for (int j = 0; j < 13; ++j) cur[12 + j] = xbuf[t256 * 13 + j];
            const float b1v = b1[t256];
            float c1 = 0, v1 = 0, s1 = 0;
            #pragma unroll
            for (int t = 0; t < TS; ++t) {
                lif_step(cur[t], b1v, c1, v1, s1);
                if (s1 != 0.0f) m1 |= (1u << t);
            }
        }
        unsigned long long bal1 = __ballot(m1 != 0u);
        if (lane == 0) waveCnt[wave] = (uint32_t)__popcll(bal1);
        __syncthreads();                            // xbuf reads done; counts published
        int base1 = 0, n1 = 0;
        #pragma unroll
        for (int w = 0; w < 4; ++w) {
            if (w < wave) base1 += (int)waveCnt[w];
            n1 += (int)waveCnt[w];
        }
        const int pos1 = base1 + (int)__popcll(bal1 & below);

        // ---- C2: windowed GEMM2 walk (K=256 plain left-assoc) + layer-2 LIF ----
        acch_zero(accW);
        for (int start = 0; start < n1; start += CAP) {
            const int end = (n1 - start < CAP) ? n1 : start + CAP;
            const int count = end - start;
            if (!isHi && m1 && pos1 >= start && pos1 < end) {
                int slot = pos1 - start;
                idxL[slot] = t256 * H;
                write_rec(recs, rec24, slot, m1);
            }
            __syncthreads();
            WALK_BODY(count, w2t, 0, accW);
            __syncthreads();
        }
        if (isHi) {
            #pragma unroll
            for (int i = 0; i < 6; ++i) {
                xbuf[t256 * 13 + 2 * i]     = accW.p[i].x;
                xbuf[t256 * 13 + 2 * i + 1] = accW.p[i].y;
            }
            xbuf[t256 * 13 + 12] = accW.last;
        }
        __syncthreads();
        uint32_t m2 = 0;
        if (!isHi) {
            float cur[TS];
            #pragma unroll
            for (int i = 0; i < 6; ++i) { cur[2 * i] = accW.p[i].x; cur[2 * i + 1] = accW.p[i].y; }
            #pragma unroll
            for (int j = 0; j < 13; ++j) cur[12 + j] = xbuf[t256 * 13 + j];
            const float b2v = b2[t256];
            float c2 = 0, v2 = 0, s2 = 0;
            #pragma unroll
            for (int t = 0; t < TS; ++t) {
                lif_step(cur[t], b2v, c2, v2, s2);
                if (s2 != 0.0f) m2 |= (1u << t);
            }
        }
        unsigned long long bal2 = __ballot(m2 != 0u);
        if (lane == 0) waveCnt[wave] = (uint32_t)__popcll(bal2);
        __syncthreads();
        int base2 = 0, n2 = 0;
        #pragma unroll
        for (int w = 0; w < 4; ++w) {
            if (w < wave) base2 += (int)waveCnt[w];
            n2 += (int)waveCnt[w];
        }
        const int pos2 = base2 + (int)__popcll(bal2 & below);

        // ---- C3: windowed GEMM3 walk + layer-3 LIF (neurons 0..79) ----
        acch_zero(accW);
        for (int start = 0; start < n2; start += CAP) {
            const int end = (n2 - start < CAP) ? n2 : start + CAP;
            const int count = end - start;
            if (!isHi && m2 && pos2 >= start && pos2 < end) {
                int slot = pos2 - start;
                idxL[slot] = t256 * OUTP;
                write_rec(recs, rec24, slot, m2);
            }
            __syncthreads();
            if (t256 < OUTP) {
                WALK_BODY(count, w3t, 0, accW);
            }
            __syncthreads();
        }
        if (isHi && t256 < OUTP) {
            #pragma unroll
            for (int i = 0; i < 6; ++i) {
                xbuf[t256 * 13 + 2 * i]     = accW.p[i].x;
                xbuf[t256 * 13 + 2 * i + 1] = accW.p[i].y;
            }
            xbuf[t256 * 13 + 12] = accW.last;
        }
        __syncthreads();
        if (!isHi && t256 < OUTP) {
            float cur[TS];
            #pragma unroll
            for (int i = 0; i < 6; ++i) { cur[2 * i] = accW.p[i].x; cur[2 * i + 1] = accW.p[i].y; }
            #pragma unroll
            for (int j = 0; j < 13; ++j) cur[12 + j] = xbuf[t256 * 13 + j];
            const float b3v = b3[t256];
            float c3 = 0, v3 = 0, s3 = 0, ct = 0;
            #pragma unroll
            for (int t = 0; t < TS; ++t) {
                lif_step(cur[t], b3v, c3, v3, s3);
                ct += s3;
            }
            cnt3[t256] = ct;
        }
        __syncthreads();

        // ---- decode: per-op rounding like np einsum (no FMA) ----
        if (tid < 8) {
            float raw = 0.0f;
            #pragma unroll
            for (int pp = 0; pp < POP; ++pp) {
                float po = __fdiv_rn(cnt3[tid * POP + pp], 25.0f);
                raw = __fadd_rn(raw, __fmul_rn(po, dw[tid * POP + pp]));
            }
            raw = __fadd_rn(raw, db[tid]);
            out[b * 8 + tid] = (float)tanh((double)raw);
        }
    }
}

extern "C" void kernel_launch(void* const* d_in, const int* in_sizes, int n_in,
                              void* d_out, int out_size, void* d_ws, size_t ws_size,
                              hipStream_t stream) {
    const float* obs   = (const float*)d_in[0];
    const float* emean = (const float*)d_in[1];
    const float* estd  = (const float*)d_in[2];
    const float* w1    = (const float*)d_in[3];
    const float* b1    = (const float*)d_in[4];
    const float* w2    = (const float*)d_in[5];
    const float* b2    = (const float*)d_in[6];
    const float* w3    = (const float*)d_in[7];
    const float* b3    = (const float*)d_in[8];
    const float* dw    = (const float*)d_in[9];
    const float* db    = (const float*)d_in[10];
    float* out = (float*)d_out;

    char* ws = (char*)d_ws;
    float* w1t = (float*)(ws);                 // 655360 * 4 = 2,621,440 B
    float* w2t = (float*)(ws + 2621440);       //  65536 * 4 =   262,144 B
    float* w3t = (float*)(ws + 2883584);       //  20480 * 4 =    81,920 B

    k0_transpose<<<728, 256, 0, stream>>>(w1, w2, w3, w1t, w2t, w3t);
    k1_fused<<<1024, 512, 0, stream>>>(obs, emean, estd, w1t, w2t, w3t,
                                       b1, b2, b3, dw, db, out);
}

// Round 4
// 510.580 us; speedup vs baseline: 1.3324x; 1.3324x over previous
//
#include <hip/hip_runtime.h>
#include <stdint.h>

#define NB 2048
#define OBSD 256
#define POP 10
#define NIN 2560       // OBS_DIM * POP_DIM
#define H 256          // HID1 == HID2
#define OUTP 80        // ACT_DIM * DE_POP
#define TS 25
#define CAP 256        // record window slots (windowed chunk loop exact for any input)

typedef __attribute__((ext_vector_type(2))) float f2;

// correctly-rounded fp32 exp (fp64 exp then round) — matches SVML high-accuracy
// expf that numpy dispatches to on AVX512 hosts (validated r8: absmax 4.8e-7).
__device__ __forceinline__ float exp_cr(float x) {
    return (float)exp((double)x);
}

__device__ __forceinline__ int rfl(int v) {
    return __builtin_amdgcn_readfirstlane(v);
}

// 25-float accumulator as 12 float2 pairs + 1 scalar (v_pk_fma_f32 path)
struct Acc25 {
    f2 p[12];
    float last;
};

__device__ __forceinline__ void acc_zero(Acc25& a) {
    #pragma unroll
    for (int i = 0; i < 12; ++i) { a.p[i].x = 0.0f; a.p[i].y = 0.0f; }
    a.last = 0.0f;
}

// fold part into acc (per-element RN add == scalar folds), zero part
__device__ __forceinline__ void acc_fold(Acc25& acc, Acc25& part) {
    #pragma unroll
    for (int i = 0; i < 12; ++i) {
        acc.p[i].x = __fadd_rn(acc.p[i].x, part.p[i].x);
        acc.p[i].y = __fadd_rn(acc.p[i].y, part.p[i].y);
        part.p[i].x = 0.0f; part.p[i].y = 0.0f;
    }
    acc.last = __fadd_rn(acc.last, part.last);
    part.last = 0.0f;
}

__device__ __forceinline__ void acc_unpack(const Acc25& a, float* __restrict__ t) {
    #pragma unroll
    for (int i = 0; i < 12; ++i) { t[2 * i] = a.p[i].x; t[2 * i + 1] = a.p[i].y; }
    t[24] = a.last;
}

// packed-byte -> f32 converts (v_cvt_f32_ubyte{0..3}); {0,1} bytes are exact.
__device__ __forceinline__ float ub0(uint32_t v) {
#if __has_builtin(__builtin_amdgcn_cvt_f32_ubyte0)
    return __builtin_amdgcn_cvt_f32_ubyte0(v);
#else
    return (float)(v & 0xffu);
#endif
}
__device__ __forceinline__ float ub1(uint32_t v) {
#if __has_builtin(__builtin_amdgcn_cvt_f32_ubyte1)
    return __builtin_amdgcn_cvt_f32_ubyte1(v);
#else
    return (float)((v >> 8) & 0xffu);
#endif
}
__device__ __forceinline__ float ub2(uint32_t v) {
#if __has_builtin(__builtin_amdgcn_cvt_f32_ubyte2)
    return __builtin_amdgcn_cvt_f32_ubyte2(v);
#else
    return (float)((v >> 16) & 0xffu);
#endif
}
__device__ __forceinline__ float ub3(uint32_t v) {
#if __has_builtin(__builtin_amdgcn_cvt_f32_ubyte3)
    return __builtin_amdgcn_cvt_f32_ubyte3(v);
#else
    return (float)((v >> 24) & 0xffu);
#endif
}

// 25-term fma chain on the BYTE record layout: 25 spike bytes {0,1} + 7 pad in
// a 32 B block (2 x ds_read_b128 — was 7 LDS ops / 100 B on the float layout;
// LDS broadcast bandwidth was the r0 bottleneck). cvt_f32_ubyte gives exact
// 0.0f/1.0f, so fma(w, bit, acc) is per-element bitwise == scalar fmaf ==
// the float-record path (validated r12/r16/r17 chain semantics).
__device__ __forceinline__ void fma25b(float w, const uint32_t* __restrict__ rec, Acc25& a) {
    f2 wp; wp.x = w; wp.y = w;
    uint4 q0 = ((const uint4*)rec)[0];
    uint4 q1 = ((const uint4*)rec)[1];
    uint32_t u[7] = {q0.x, q0.y, q0.z, q0.w, q1.x, q1.y, q1.z};
    #pragma unroll
    for (int i = 0; i < 6; ++i) {
        f2 lo, hi;
        lo.x = ub0(u[i]); lo.y = ub1(u[i]);
        hi.x = ub2(u[i]); hi.y = ub3(u[i]);
#if __has_builtin(__builtin_elementwise_fma)
        a.p[2 * i]     = __builtin_elementwise_fma(wp, lo, a.p[2 * i]);
        a.p[2 * i + 1] = __builtin_elementwise_fma(wp, hi, a.p[2 * i + 1]);
#else
        a.p[2 * i].x = fmaf(w, lo.x, a.p[2 * i].x);
        a.p[2 * i].y = fmaf(w, lo.y, a.p[2 * i].y);
        a.p[2 * i + 1].x = fmaf(w, hi.x, a.p[2 * i + 1].x);
        a.p[2 * i + 1].y = fmaf(w, hi.y, a.p[2 * i + 1].y);
#endif
    }
    a.last = fmaf(w, ub0(u[6]), a.last);
}

// spread 4 mask bits into 4 bytes of a u32 (each byte 0 or 1)
__device__ __forceinline__ uint32_t expand4(uint32_t b) {
    return (b & 1u) | ((b & 2u) << 7) | ((b & 4u) << 14) | ((b & 8u) << 21);
}

// write one row record: 25 spike bytes {0,1} + 7 pad = 32 B (2 x uint4 stores)
__device__ __forceinline__ void write_rec(uint32_t* __restrict__ recB, int pos, uint32_t m) {
    uint4 a, c;
    a.x = expand4(m);        a.y = expand4(m >> 4);
    a.z = expand4(m >> 8);   a.w = expand4(m >> 12);
    c.x = expand4(m >> 16);  c.y = expand4(m >> 20);
    c.z = expand4(m >> 24);  c.w = 0u;
    uint4* dst = (uint4*)&recB[pos * 8];
    dst[0] = a; dst[1] = c;
}

// sorted-index event walk, 4-deep weight prefetch, macro form (textual — no
// reference params: r1's reference-select walk spilled an Acc25 to scratch;
// r2/r3's tight VGPR budgets spilled the accumulators entirely). DOFOLD is a
// literal 0/1; TGT is the accumulator VARIABLE fma25b targets.
// Uses in-scope: idxL, recB, tid, acc, part, nextB.
#define WALK_BODY(CNT, WT, DOFOLD, TGT)                                        \
  do {                                                                         \
    const int _n = (CNT);                                                      \
    int _pi0 = 0, _pi1 = 0, _pi2 = 0, _pi3 = 0;                                \
    float _pw0 = 0, _pw1 = 0, _pw2 = 0, _pw3 = 0;                              \
    if (_n > 0) { _pi0 = rfl(idxL[0]); _pw0 = (WT)[_pi0 + tid]; }              \
    if (_n > 1) { _pi1 = rfl(idxL[1]); _pw1 = (WT)[_pi1 + tid]; }              \
    if (_n > 2) { _pi2 = rfl(idxL[2]); _pw2 = (WT)[_pi2 + tid]; }              \
    if (_n > 3) { _pi3 = rfl(idxL[3]); _pw3 = (WT)[_pi3 + tid]; }              \
    int _j = 0;                                                                \
    for (; _j + 4 <= _n; _j += 4) {                                            \
      int _c0 = _pi0, _c1 = _pi1, _c2 = _pi2, _c3 = _pi3;                      \
      float _w0 = _pw0, _w1 = _pw1, _w2 = _pw2, _w3 = _pw3;                    \
      if (_j + 4 < _n) { _pi0 = rfl(idxL[_j + 4]); _pw0 = (WT)[_pi0 + tid]; }  \
      if (_j + 5 < _n) { _pi1 = rfl(idxL[_j + 5]); _pw1 = (WT)[_pi1 + tid]; }  \
      if (_j + 6 < _n) { _pi2 = rfl(idxL[_j + 6]); _pw2 = (WT)[_pi2 + tid]; }  \
      if (_j + 7 < _n) { _pi3 = rfl(idxL[_j + 7]); _pw3 = (WT)[_pi3 + tid]; }  \
      if (DOFOLD) { while (_c0 >= nextB) { acc_fold(acc, part); nextB += 320 * H; } } \
      fma25b(_w0, &recB[_j * 8], TGT);                                         \
      if (DOFOLD) { while (_c1 >= nextB) { acc_fold(acc, part); nextB += 320 * H; } } \
      fma25b(_w1, &recB[(_j + 1) * 8], TGT);                                   \
      if (DOFOLD) { while (_c2 >= nextB) { acc_fold(acc, part); nextB += 320 * H; } } \
      fma25b(_w2, &recB[(_j + 2) * 8], TGT);                                   \
      if (DOFOLD) { while (_c3 >= nextB) { acc_fold(acc, part); nextB += 320 * H; } } \
      fma25b(_w3, &recB[(_j + 3) * 8], TGT);                                   \
    }                                                                          \
    for (; _j < _n; ++_j) {                                                    \
      int _ii = rfl(idxL[_j]); float _wv = (WT)[_ii + tid];                    \
      if (DOFOLD) { while (_ii >= nextB) { acc_fold(acc, part); nextB += 320 * H; } } \
      fma25b(_wv, &recB[_j * 8], TGT);                                         \
    }                                                                          \
  } while (0)

// ---------------- K0: COALESCED tiled transposes into fp32 [k][n] layouts ----------------
__global__ __launch_bounds__(256) void k0_transpose(
    const float* __restrict__ w1, const float* __restrict__ w2, const float* __restrict__ w3,
    float* __restrict__ w1t, float* __restrict__ w2t, float* __restrict__ w3t)
{
    __shared__ float tile[32][33];
    int bid = blockIdx.x;
    const float* src; float* dst; int R, C, tr, tc;
    if (bid < 640)      { src = w1; dst = w1t; R = 256; C = NIN; tr = bid / 80; tc = bid % 80; }
    else if (bid < 704) { int t = bid - 640; src = w2; dst = w2t; R = 256; C = 256; tr = t / 8; tc = t % 8; }
    else                { int t = bid - 704; src = w3; dst = w3t; R = OUTP; C = 256; tr = t / 8; tc = t % 8; }
    const int tx = threadIdx.x & 31, ty = threadIdx.x >> 5;
    const int r0 = tr * 32, c0 = tc * 32;
    #pragma unroll
    for (int i = 0; i < 4; ++i) {
        int r = r0 + ty + i * 8, c = c0 + tx;
        if (r < R && c < C) tile[ty + i * 8][tx] = src[r * C + c];
    }
    __syncthreads();
    // dst is [C][R]
    #pragma unroll
    for (int i = 0; i < 4; ++i) {
        int c = c0 + ty + i * 8, r = r0 + tx;
        if (c < C && r < R) dst[c * R + r] = tile[tx][ty + i * 8];
    }
}

// One LIF step, numpy-faithful per-op rounding. vth feeds ONLY the comparison,
// so decide the spike via certified interval from fast fp32 exp (~3 ulp) on a
// division-free argument d*(1/3); margin widened to cover the extra
// ~1.5e-7*|ag| relative arg error. Exact __fdiv_rn + exp_cr fallback only when
// |v - vth_a| <= delta (rare) — decisions provably identical (validated r2/r3).
__device__ __forceinline__ void lif_step(float x, float bv, float& c, float& v, float& s) {
    float cn = __fadd_rn(__fadd_rn(__fmul_rn(c, 0.5f), x), bv);
    c = cn;
    float vp = v;
    float t  = __fmul_rn(__fmul_rn(vp, 0.75f), __fadd_rn(1.0f, -s));
    float vn = __fadd_rn(t, cn);
    float d  = __fadd_rn(vp, -vn);
    v = vn;
    float ag_f  = __fmul_rn(d, 0.33333334f);        // fast approx of d/3
    float ex_a  = __expf(ag_f);                     // fast f32 exp (v_exp_f32)
    float vth_a = 0.25f + 0.5f * (ex_a - 1.0f);
    float delta = (1e-5f + 1e-6f * fabsf(ag_f)) * (ex_a + fabsf(vth_a) + 1.0f);
    if (vn > vth_a + delta) {
        s = 1.0f;
    } else if (vn < vth_a - delta) {
        s = 0.0f;
    } else {                                        // exact fallback (rare)
        float ag  = __fdiv_rn(d, 3.0f);
        float ex  = exp_cr(ag);
        float vth = __fadd_rn(0.25f, __fmul_rn(0.5f, __fadd_rn(ex, -1.0f)));
        s = (vn > vth) ? 1.0f : 0.0f;
    }
}

// ---------------- K1: fused, ONE batch row per block (2048 blocks) ----------------
// Geometry reverted to the proven r0 shape: 256 threads, 5 blocks/CU (~100-reg
// budget, zero spills). The change vs r0/r1 is the record format: 32-byte
// byte-records cut LDS broadcast traffic 3.1x (the measured ~69 TB/s LDS
// ceiling was the r0 bottleneck), paid with +25 v_cvt_f32_ubyte VALU per row.
__global__ __launch_bounds__(256, 5) void k1_fused(
    const float* __restrict__ obs, const float* __restrict__ emean, const float* __restrict__ estd,
    const float* __restrict__ w1t, const float* __restrict__ w2t, const float* __restrict__ w3t,
    const float* __restrict__ b1, const float* __restrict__ b2, const float* __restrict__ b3,
    const float* __restrict__ dw, const float* __restrict__ db, float* __restrict__ out)
{
    __shared__ __align__(16) uint32_t recB[CAP * 8];  // 8,192 B byte-records
    __shared__ int   idxL[CAP];                       // 1,024 B premult indices
    __shared__ uint32_t cntA[40];                     //   160 B per-group per-wave counts
    __shared__ uint32_t gbase[11];                    //    44 B group position prefix
    __shared__ uint32_t waveCnt[4];
    __shared__ float cnt3[OUTP];

    const int tid = threadIdx.x;
    const int wave = tid >> 6, lane = tid & 63;
    const int b = blockIdx.x;
    const unsigned long long below = (1ull << lane) - 1ull;

    // ---- Phase A: population encoding, numpy-faithful fp32 op-by-op.
    // Monotonicity screen: arg < -3.23 => a < 0.0396 => 25a(1+eps) < 0.991
    // < 0.999 => mask provably 0 with NO exp call (validated r17). ----
    uint32_t msk[10];
    #pragma unroll
    for (int k = 0; k < 10; ++k) {
        int i = k * 256 + tid;
        int o = i / 10;
        float x  = obs[b * OBSD + o];
        float mu = emean[i];
        float sd = estd[i];
        float dd = __fadd_rn(x, -mu);
        float d2 = __fmul_rn(dd, dd);
        float nm = __fmul_rn(-0.5f, d2);
        float dn = __fmul_rn(sd, sd);
        float arg = __fdiv_rn(nm, dn);
        uint32_t m = 0;
        if (arg >= -3.23f) {
            float a  = exp_cr(arg);
            float volt = 0.0f;
            #pragma unroll
            for (int t = 0; t < TS; ++t) {
                volt = __fadd_rn(volt, a);
                if (volt > 0.999f) { m |= (1u << t); volt = __fadd_rn(volt, -0.999f); }
            }
        }
        msk[k] = m;
    }
    // publish all 10 group counts at once
    #pragma unroll
    for (int k = 0; k < 10; ++k) {
        unsigned long long bal = __ballot(msk[k] != 0u);
        if (lane == 0) cntA[k * 4 + wave] = (uint32_t)__popcll(bal);
    }
    __syncthreads();
    if (tid == 0) {                                 // group position prefix sums
        uint32_t run = 0;
        #pragma unroll
        for (int k = 0; k < 10; ++k) {
            gbase[k] = run;
            run += cntA[k * 4] + cntA[k * 4 + 1] + cntA[k * 4 + 2] + cntA[k * 4 + 3];
        }
        gbase[10] = run;
    }
    __syncthreads();
    const int nTot = (int)gbase[10];

    // ---- Phase B: event GEMM1, windowed chunk loop over global sorted
    // positions (exact for any input). Fold boundaries {320 x 8} ride on
    // premult idx values — identical FP order per element. ----
    Acc25 acc, part;
    acc_zero(acc); acc_zero(part);
    int nextB = 320 * H;

    for (int start = 0; start < nTot; start += CAP) {
        const int end = (nTot - start < CAP) ? nTot : start + CAP;
        const int count = end - start;
        #pragma unroll
        for (int k = 0; k < 10; ++k) {
            int gb = (int)gbase[k], ge = (int)gbase[k + 1];
            if (ge <= start || gb >= end) continue;
            uint32_t m = msk[k];
            unsigned long long bal = __ballot(m != 0u);
            if (m) {
                int pre = 0;
                #pragma unroll
                for (int w = 0; w < 4; ++w) if (w < wave) pre += (int)cntA[k * 4 + w];
                int pos = gb + pre + (int)__popcll(bal & below);
                if (pos >= start && pos < end) {
                    int slot = pos - start;
                    idxL[slot] = (k * 256 + tid) * H;
                    write_rec(recB, slot, m);
                }
            }
        }
        __syncthreads();                            // records complete
        WALK_BODY(count, w1t, 1, part);
        __syncthreads();                            // walk reads done
    }
    acc_fold(acc, part);                            // final fold

    // ---- C1: layer-1 LIF, all 25 steps ----
    uint32_t m1 = 0;
    {
        float cur[TS];
        acc_unpack(acc, cur);
        const float b1v = b1[tid];
        float c1 = 0, v1 = 0, s1 = 0;
        #pragma unroll
        for (int t = 0; t < TS; ++t) {
            lif_step(cur[t], b1v, c1, v1, s1);
            if (s1 != 0.0f) m1 |= (1u << t);
        }
    }
    unsigned long long bal1 = __ballot(m1 != 0u);
    if (lane == 0) waveCnt[wave] = (uint32_t)__popcll(bal1);
    __syncthreads();                                // counts published
    int base1 = 0, n1 = 0;
    #pragma unroll
    for (int w = 0; w < 4; ++w) {
        if (w < wave) base1 += (int)waveCnt[w];
        n1 += (int)waveCnt[w];
    }
    if (m1) {                                       // n1 <= 256: single window
        int pos = base1 + (int)__popcll(bal1 & below);
        idxL[pos] = tid * H;
        write_rec(recB, pos, m1);
    }
    __syncthreads();

    // ---- C2: batched GEMM2 walk (K=256, single window) + layer-2 LIF ----
    Acc25 acc2;
    acc_zero(acc2);
    WALK_BODY(n1, w2t, 0, acc2);
    uint32_t m2 = 0;
    {
        float cur[TS];
        acc_unpack(acc2, cur);
        const float b2v = b2[tid];
        float c2 = 0, v2 = 0, s2 = 0;
        #pragma unroll
        for (int t = 0; t < TS; ++t) {
            lif_step(cur[t], b2v, c2, v2, s2);
            if (s2 != 0.0f) m2 |= (1u << t);
        }
    }
    unsigned long long bal2 = __ballot(m2 != 0u);
    if (lane == 0) waveCnt[wave] = (uint32_t)__popcll(bal2);
    __syncthreads();                                // C2 walk reads done; counts published
    int base2 = 0, n2 = 0;
    #pragma unroll
    for (int w = 0; w < 4; ++w) {
        if (w < wave) base2 += (int)waveCnt[w];
        n2 += (int)waveCnt[w];
    }
    if (m2) {                                       // n2 <= 256: single window
        int pos = base2 + (int)__popcll(bal2 & below);
        idxL[pos] = tid * OUTP;
        write_rec(recB, pos, m2);
    }
    __syncthreads();

    // ---- C3: batched GEMM3 walk + layer-3 LIF (threads 0..79) ----
    if (tid < OUTP) {
        Acc25 x3;
        acc_zero(x3);
        WALK_BODY(n2, w3t, 0, x3);
        float cur[TS];
        acc_unpack(x3, cur);
        const float b3v = b3[tid];
        float c3 = 0, v3 = 0, s3 = 0, ct = 0;
        #pragma unroll
        for (int t = 0; t < TS; ++t) {
            lif_step(cur[t], b3v, c3, v3, s3);
            ct += s3;
        }
        cnt3[tid] = ct;
    }
    __syncthreads();

    // ---- decode: per-op rounding like np einsum (no FMA) ----
    if (tid < 8) {
        float raw = 0.0f;
        #pragma unroll
        for (int pp = 0; pp < POP; ++pp) {
            float po = __fdiv_rn(cnt3[tid * POP + pp], 25.0f);
            raw = __fadd_rn(raw, __fmul_rn(po, dw[tid * POP + pp]));
        }
        raw = __fadd_rn(raw, db[tid]);
        out[b * 8 + tid] = (float)tanh((double)raw);
    }
}

extern "C" void kernel_launch(void* const* d_in, const int* in_sizes, int n_in,
                              void* d_out, int out_size, void* d_ws, size_t ws_size,
                              hipStream_t stream) {
    const float* obs   = (const float*)d_in[0];
    const float* emean = (const float*)d_in[1];
    const float* estd  = (const float*)d_in[2];
    const float* w1    = (const float*)d_in[3];
    const float* b1    = (const float*)d_in[4];
    const float* w2    = (const float*)d_in[5];
    const float* b2    = (const float*)d_in[6];
    const float* w3    = (const float*)d_in[7];
    const float* b3    = (const float*)d_in[8];
    const float* dw    = (const float*)d_in[9];
    const float* db    = (const float*)d_in[10];
    float* out = (float*)d_out;

    char* ws = (char*)d_ws;
    float* w1t = (float*)(ws);                 // 655360 * 4 = 2,621,440 B
    float* w2t = (float*)(ws + 2621440);       //  65536 * 4 =   262,144 B
    float* w3t = (float*)(ws + 2883584);       //  20480 * 4 =    81,920 B

    k0_transpose<<<728, 256, 0, stream>>>(w1, w2, w3, w1t, w2t, w3t);
    k1_fused<<<NB, 256, 0, stream>>>(obs, emean, estd, w1t, w2t, w3t,
                                     b1, b2, b3, dw, db, out);
}